// Round 1
// 782.784 us; speedup vs baseline: 1.0840x; 1.0840x over previous
//
#include <hip/hip_runtime.h>

#define N_LSTM 16
#define ISZ 128
#define HSZ 128
#define BSZ 32
#define TSZ 512
#define G4H 512
#define XROW (N_LSTM * ISZ)   // 2048
#define OROW (N_LSTM * HSZ)   // 2048

typedef __attribute__((ext_vector_type(8))) short s16x8;
typedef __attribute__((ext_vector_type(4))) float f32x4;

static __device__ __forceinline__ unsigned short f2bf(float f) {
    unsigned int u = __builtin_bit_cast(unsigned int, f);
    u += 0x7fffu + ((u >> 16) & 1u);
    return (unsigned short)(u >> 16);
}

static __device__ __forceinline__ float fast_sigmoid(float x) {
    float e = __expf(-x);
    return __builtin_amdgcn_rcpf(1.0f + e);
}

static __device__ __forceinline__ float fast_tanh(float x) {
    x = fminf(fmaxf(x, -20.0f), 20.0f);
    float e = __expf(-2.0f * x);
    return (1.0f - e) * __builtin_amdgcn_rcpf(1.0f + e);
}

// lgkm-only barrier: syncs LDS producers/consumers WITHOUT draining vmcnt,
// so the epilogue's global stores (and the x prefetch load) stay in flight
// across the per-step barrier. __syncthreads would emit s_waitcnt vmcnt(0).
static __device__ __forceinline__ void barrier_lgkm() {
    __builtin_amdgcn_sched_barrier(0);
    asm volatile("s_waitcnt lgkmcnt(0)" ::: "memory");
    __builtin_amdgcn_s_barrier();
    __builtin_amdgcn_sched_barrier(0);
}

// One workgroup = (n, batch-half of 16). 8 waves; wave w owns hidden units
// [16w, 16w+16) x all 4 gates. W_ih / W_hh held in registers as MFMA
// B-fragments. h round-trips through LDS (bf16, double-buffered) each step.
// x-projection xacc(t+1) = bias + Wih*x(t+1) is computed one step AHEAD
// (during step t), so the post-barrier critical path is only the 4-deep
// W_hh*h MFMA chain; the x-MFMAs overlap the epilogue VALU on the MFMA pipe.
__global__ __launch_bounds__(512, 2) void widelstm_fused(
    const float* __restrict__ x, const float* __restrict__ Wih,
    const float* __restrict__ Whh, const float* __restrict__ bih,
    const float* __restrict__ bhh, float* __restrict__ out)
{
    __shared__ __align__(16) unsigned short xbuf[2][16][136];
    __shared__ __align__(16) unsigned short hbuf[2][16][136];

    const int tid = threadIdx.x;
    const int wv  = tid >> 6;        // wave 0..7 -> hid chunk
    const int ln  = tid & 63;
    const int lm  = ln & 15;         // A-row (m) / C-col
    const int lq  = ln >> 4;         // quad
    const int n    = blockIdx.x >> 1;
    const int half = blockIdx.x & 1;
    const int b0   = half * 16;

    // ---- Load weight B-fragments (once). B[k][col]: lane holds col=lm, k=lq*8+j.
    s16x8 wih[4][4], whh[4][4];
    float bias[4];
    #pragma unroll
    for (int g = 0; g < 4; ++g) {
        const int col = g * 128 + wv * 16 + lm;   // gate-output index in 4H
        bias[g] = bih[n * G4H + col] + bhh[n * G4H + col];
        #pragma unroll
        for (int kt = 0; kt < 4; ++kt) {
            const float* pi = Wih + ((size_t)n * G4H + col) * ISZ + kt * 32 + lq * 8;
            const float* ph = Whh + ((size_t)n * G4H + col) * HSZ + kt * 32 + lq * 8;
            s16x8 a, b;
            #pragma unroll
            for (int j = 0; j < 8; ++j) {
                a[j] = (short)f2bf(pi[j]);
                b[j] = (short)f2bf(ph[j]);
            }
            wih[g][kt] = a;
            whh[g][kt] = b;
        }
    }

    // zero hbuf[0] (h(-1) = 0); hbuf[1] is produced at t=0 before first read
    for (int i = tid; i < 16 * 136; i += 512)
        ((unsigned short*)hbuf[0])[i] = 0;

    // ---- x staging: thread loads 4 consecutive floats of one row per step
    const int sr = tid >> 5;         // 0..15 : batch row within half
    const int sc = (tid & 31) * 4;   // 0..124 : col
    const float* xrow = x + (size_t)(b0 + sr) * TSZ * XROW + n * ISZ + sc;

    // ---- prologue: stage x(0), compute xacc(0) = bias + Wih*x(0)
    float4 xr = *(const float4*)(xrow);
    {
        unsigned int lo = (unsigned int)f2bf(xr.x) | ((unsigned int)f2bf(xr.y) << 16);
        unsigned int hi = (unsigned int)f2bf(xr.z) | ((unsigned int)f2bf(xr.w) << 16);
        *(uint2*)&xbuf[0][sr][sc] = make_uint2(lo, hi);
    }
    barrier_lgkm();

    f32x4 xacc[4];
    #pragma unroll
    for (int g = 0; g < 4; ++g)
        xacc[g] = (f32x4){bias[g], bias[g], bias[g], bias[g]};
    #pragma unroll
    for (int kt = 0; kt < 4; ++kt) {
        s16x8 axk = *(const s16x8*)&xbuf[0][lm][kt * 32 + lq * 8];
        #pragma unroll
        for (int g = 0; g < 4; ++g)
            xacc[g] = __builtin_amdgcn_mfma_f32_16x16x32_bf16(axk, wih[g][kt], xacc[g], 0, 0, 0);
    }

    xr = *(const float4*)(xrow + (size_t)XROW);   // prefetch x(1)

    float cprev[4] = {0.f, 0.f, 0.f, 0.f};
    float hlast[4] = {0.f, 0.f, 0.f, 0.f};
    const int ocol = n * HSZ + wv * 16 + lm;

    // Step t: entering with xacc = bias + Wih*x(t), hbuf[CUR] = h(t-1) (bf16),
    // xr = x(t+1). Stages x(t+1), computes h(t), and xacc for t+1.
#define LSTM_STEP(T_, CUR_, NXT_)                                                          \
    {                                                                                      \
        const int t_ = (T_);                                                               \
        if (t_ + 1 < TSZ) {                                                                \
            unsigned int lo = (unsigned int)f2bf(xr.x) | ((unsigned int)f2bf(xr.y) << 16); \
            unsigned int hi = (unsigned int)f2bf(xr.z) | ((unsigned int)f2bf(xr.w) << 16); \
            *(uint2*)&xbuf[NXT_][sr][sc] = make_uint2(lo, hi);                             \
        }                                                                                  \
        barrier_lgkm();  /* h(t-1) writes + x(t+1) staging now visible */                  \
        s16x8 ah0 = *(const s16x8*)&hbuf[CUR_][lm][0 * 32 + lq * 8];                       \
        s16x8 ah1 = *(const s16x8*)&hbuf[CUR_][lm][1 * 32 + lq * 8];                       \
        s16x8 ah2 = *(const s16x8*)&hbuf[CUR_][lm][2 * 32 + lq * 8];                       \
        s16x8 ah3 = *(const s16x8*)&hbuf[CUR_][lm][3 * 32 + lq * 8];                       \
        if (t_ + 2 < TSZ)                                                                  \
            xr = *(const float4*)(xrow + (size_t)(t_ + 2) * XROW);                         \
        f32x4 hacc[4];                                                                     \
        _Pragma("unroll")                                                                  \
        for (int g = 0; g < 4; ++g)                                                        \
            hacc[g] = __builtin_amdgcn_mfma_f32_16x16x32_bf16(ah0, whh[g][0], xacc[g], 0, 0, 0); \
        _Pragma("unroll")                                                                  \
        for (int g = 0; g < 4; ++g)                                                        \
            hacc[g] = __builtin_amdgcn_mfma_f32_16x16x32_bf16(ah1, whh[g][1], hacc[g], 0, 0, 0); \
        _Pragma("unroll")                                                                  \
        for (int g = 0; g < 4; ++g)                                                        \
            hacc[g] = __builtin_amdgcn_mfma_f32_16x16x32_bf16(ah2, whh[g][2], hacc[g], 0, 0, 0); \
        _Pragma("unroll")                                                                  \
        for (int g = 0; g < 4; ++g)                                                        \
            hacc[g] = __builtin_amdgcn_mfma_f32_16x16x32_bf16(ah3, whh[g][3], hacc[g], 0, 0, 0); \
        if (t_ + 1 < TSZ) { /* x-projection for t+1: off the critical path */              \
            _Pragma("unroll")                                                              \
            for (int g = 0; g < 4; ++g)                                                    \
                xacc[g] = (f32x4){bias[g], bias[g], bias[g], bias[g]};                     \
            _Pragma("unroll")                                                              \
            for (int kt = 0; kt < 4; ++kt) {                                               \
                s16x8 axk = *(const s16x8*)&xbuf[NXT_][lm][kt * 32 + lq * 8];              \
                _Pragma("unroll")                                                          \
                for (int g = 0; g < 4; ++g)                                                \
                    xacc[g] = __builtin_amdgcn_mfma_f32_16x16x32_bf16(axk, wih[g][kt], xacc[g], 0, 0, 0); \
            }                                                                              \
        }                                                                                  \
        float* orow = out + (size_t)t_ * OROW + ocol;                                      \
        _Pragma("unroll")                                                                  \
        for (int r = 0; r < 4; ++r) {                                                      \
            float iv = fast_sigmoid(hacc[0][r]);                                           \
            float fv = fast_sigmoid(hacc[1][r]);                                           \
            float gv = fast_tanh(hacc[2][r]);                                              \
            float ov = fast_sigmoid(hacc[3][r]);                                           \
            float c  = fv * cprev[r] + iv * gv;                                            \
            cprev[r] = c;                                                                  \
            float hv = ov * fast_tanh(c);                                                  \
            hlast[r] = hv;                                                                 \
            const int row = lq * 4 + r;                                                    \
            orow[(size_t)(b0 + row) * TSZ * OROW] = hv;                                    \
            hbuf[NXT_][row][wv * 16 + lm] = f2bf(hv);                                      \
        }                                                                                  \
    }

    for (int t = 0; t < TSZ; t += 2) {
        LSTM_STEP(t, 0, 1);
        LSTM_STEP(t + 1, 1, 0);
    }
#undef LSTM_STEP

    // finals: h_n, c_n  [1, B, N*H] each
    const size_t hn_off = (size_t)BSZ * TSZ * OROW;
    const size_t cn_off = hn_off + (size_t)BSZ * OROW;
    #pragma unroll
    for (int r = 0; r < 4; ++r) {
        const int row = lq * 4 + r;
        const size_t idx = (size_t)(b0 + row) * OROW + ocol;
        out[hn_off + idx] = hlast[r];
        out[cn_off + idx] = cprev[r];
    }
}

extern "C" void kernel_launch(void* const* d_in, const int* in_sizes, int n_in,
                              void* d_out, int out_size, void* d_ws, size_t ws_size,
                              hipStream_t stream) {
    const float* x   = (const float*)d_in[0];
    const float* Wih = (const float*)d_in[1];
    const float* Whh = (const float*)d_in[2];
    const float* bih = (const float*)d_in[3];
    const float* bhh = (const float*)d_in[4];
    float* out = (float*)d_out;
    widelstm_fused<<<dim3(32), dim3(512), 0, stream>>>(x, Wih, Whh, bih, bhh, out);
}